// Round 2
// baseline (395.004 us; speedup 1.0000x reference)
//
#include <hip/hip_runtime.h>

#define B_ROWS 32768
#define NIN 41
#define NL2 4
#define NRC 8
#define ROW_F 1344   // LDS floats per staged rpg row (5376 B, 16B-aligned stride)

// clamp via single v_med3_f32
__device__ __forceinline__ float med3(float v, float lo, float hi) {
    return __builtin_amdgcn_fmed3f(v, lo, hi);
}

__device__ __forceinline__ float rl63(float v) {
    return __int_as_float(__builtin_amdgcn_readlane(__float_as_int(v), 63));
}

// async global->LDS, 16B per lane; dest is wave-uniform base + lane*16
__device__ __forceinline__ void stage16(const float* g, float* l) {
    __builtin_amdgcn_global_load_lds(
        (const __attribute__((address_space(1))) void*)g,
        (__attribute__((address_space(3))) void*)l,
        16, 0, 0);
}

// ---- fused-DPP batched wave reductions (one v_add_f32_dpp per step) -------
#define DPP8(C) \
    "v_add_f32_dpp %0, %0, %0 " C " row_mask:0xf bank_mask:0xf bound_ctrl:0\n\t" \
    "v_add_f32_dpp %1, %1, %1 " C " row_mask:0xf bank_mask:0xf bound_ctrl:0\n\t" \
    "v_add_f32_dpp %2, %2, %2 " C " row_mask:0xf bank_mask:0xf bound_ctrl:0\n\t" \
    "v_add_f32_dpp %3, %3, %3 " C " row_mask:0xf bank_mask:0xf bound_ctrl:0\n\t" \
    "v_add_f32_dpp %4, %4, %4 " C " row_mask:0xf bank_mask:0xf bound_ctrl:0\n\t" \
    "v_add_f32_dpp %5, %5, %5 " C " row_mask:0xf bank_mask:0xf bound_ctrl:0\n\t" \
    "v_add_f32_dpp %6, %6, %6 " C " row_mask:0xf bank_mask:0xf bound_ctrl:0\n\t" \
    "v_add_f32_dpp %7, %7, %7 " C " row_mask:0xf bank_mask:0xf bound_ctrl:0\n\t"

__device__ __forceinline__ void wave_sum8(float* v) {
    asm("s_nop 1\n\t"
        DPP8("row_shr:1")
        DPP8("row_shr:2")
        DPP8("row_shr:4")
        DPP8("row_shr:8")
        DPP8("row_bcast:15")
        DPP8("row_bcast:31")
        "s_nop 1"
        : "+v"(v[0]), "+v"(v[1]), "+v"(v[2]), "+v"(v[3]),
          "+v"(v[4]), "+v"(v[5]), "+v"(v[6]), "+v"(v[7]));
}

#define DPP4(C) \
    "v_add_f32_dpp %0, %0, %0 " C " row_mask:0xf bank_mask:0xf bound_ctrl:0\n\t" \
    "v_add_f32_dpp %1, %1, %1 " C " row_mask:0xf bank_mask:0xf bound_ctrl:0\n\t" \
    "v_add_f32_dpp %2, %2, %2 " C " row_mask:0xf bank_mask:0xf bound_ctrl:0\n\t" \
    "v_add_f32_dpp %3, %3, %3 " C " row_mask:0xf bank_mask:0xf bound_ctrl:0\n\t"

__device__ __forceinline__ void wave_sum4(float* v) {
    asm("s_nop 1\n\t"
        DPP4("row_shr:1")
        DPP4("row_shr:2")
        DPP4("row_shr:4")
        DPP4("row_shr:8")
        DPP4("row_bcast:15")
        DPP4("row_bcast:31")
        "s_nop 1"
        : "+v"(v[0]), "+v"(v[1]), "+v"(v[2]), "+v"(v[3]));
}

__device__ __forceinline__ void blur8(float* v) {
    float t[NRC];
    #pragma unroll
    for (int r = 0; r < NRC; ++r) {
        float s = 0.8f * v[r];
        if (r > 0)       s += 0.1f * v[r - 1];
        if (r < NRC - 1) s += 0.1f * v[r + 1];
        t[r] = s;
    }
    #pragma unroll
    for (int r = 0; r < NRC; ++r) v[r] = t[r];
}

__device__ __forceinline__ void blur4(float* v) {
    float t[NL2];
    #pragma unroll
    for (int o = 0; o < NL2; ++o) {
        float s = 0.8f * v[o];
        if (o > 0)       s += 0.1f * v[o - 1];
        if (o < NL2 - 1) s += 0.1f * v[o + 1];
        t[o] = s;
    }
    #pragma unroll
    for (int o = 0; o < NL2; ++o) v[o] = t[o];
}

// launch_bounds(256,6): cap VGPR ~85 -> 6 waves/SIMD (24 waves/CU), LDS
// 21504B/block allows 6+ blocks/CU; occupancy was register-capped at 4/SIMD.
__global__ void __launch_bounds__(256, 6) pgnet_kernel(
    const float* __restrict__ inp,
    const float* __restrict__ fpg_w,
    const float* __restrict__ fpg_b,
    const float* __restrict__ rpg_w,
    const float* __restrict__ rpg_b,
    const float* __restrict__ pgw,   // [8,86]
    const float* __restrict__ pgb,   // [8]
    float* __restrict__ out)
{
    __shared__ __align__(16) float lds_rw[4][ROW_F];

    const int lane = threadIdx.x & 63;
    const int w    = threadIdx.x >> 6;
    const int row  = blockIdx.x * 4 + w;
    const bool act = lane < NIN;
    const int safe = act ? lane : (NIN - 1);   // in-bounds address for all lanes

    // ---- group 1: pgctrl table (fused w1+w2), input, biases ----
    float ws[NRC];
    #pragma unroll
    for (int r = 0; r < NRC; ++r)
        ws[r] = pgw[r * 86 + safe] + pgw[r * 86 + 45 + safe];
    const float x_raw = inp[row * NIN + safe];
    const float4 fbv  = *(const float4*)(fpg_b + (size_t)row * NL2); // wave-uniform
    const float  rb_r = rpg_b[row * NIN + safe];
    __builtin_amdgcn_sched_barrier(0);

    // ---- group 2: fpg_w[b,o,i,r] into regs (only register payload kept) ----
    const float* fp = fpg_w + (size_t)row * 1312 + (size_t)safe * 8;
    float4 fwv[NL2][2];
    #pragma unroll
    for (int o = 0; o < NL2; ++o) {
        fwv[o][0] = *(const float4*)(fp + o * 328);
        fwv[o][1] = *(const float4*)(fp + o * 328 + 4);
    }
    __builtin_amdgcn_sched_barrier(0);

    // ---- group 3: stage rpg_w row into LDS, fully coalesced (1KB/instr) ----
    // LDS chunk d = k*64+lane holds global 16B-chunk (i*8 + j) where
    // i = d>>3, j = (d&7) ^ (i&7)  -> read-side XOR swizzle spreads the
    // per-lane 128B rows across all 8 bank-groups (conflict-free b128 reads).
    const float* rbase = rpg_w + (size_t)row * 1312;
    float* lbase = &lds_rw[w][0];
    #pragma unroll
    for (int k = 0; k < 5; ++k) {
        const int d = k * 64 + lane;
        const int i = d >> 3;
        const int j = (d & 7) ^ (i & 7);
        stage16(rbase + i * 32 + j * 4, lbase + k * 256);
    }
    if (lane < 8) {                    // tail: chunks 320..327 (i = 40)
        stage16(rbase + 40 * 32 + lane * 4, lbase + 5 * 256);
    }
    __builtin_amdgcn_sched_barrier(0);
    // ========================================================================

    const float x  = act ? x_raw : 0.0f;
    const float rb = act ? rb_r  : 0.0f;

    // A[r] = pgb[r] + sum_i x_i*(W[r,i]+W[r,45+i]) -- runs under load shadow
    float t8[NRC];
    #pragma unroll
    for (int r = 0; r < NRC; ++r) t8[r] = x * ws[r];
    wave_sum8(t8);
    float A[NRC];
    #pragma unroll
    for (int r = 0; r < NRC; ++r) A[r] = rl63(t8[r]) + pgb[r];

    const float fb[NL2] = {fbv.x, fbv.y, fbv.z, fbv.w};

    float l1, rcv[NRC], l2v[NL2];

    // ---------------- iteration 1 (l1i == 0 -> no corr) ----------------
    #pragma unroll
    for (int r = 0; r < NRC; ++r) {
        const float pre = A[r];
        const float v = (pre >= 0.f) ? pre : 0.2f * pre;
        rcv[r] = med3(0.4f * v, -0.2f, 1.0f);
    }
    blur8(rcv); blur8(rcv); blur8(rcv);

    // clamp fpg weights (first vmem wait: staging still in flight behind it)
    float fw[NL2][NRC];
    #pragma unroll
    for (int o = 0; o < NL2; ++o) {
        fw[o][0] = med3(fwv[o][0].x, -1.f, 1.f); fw[o][1] = med3(fwv[o][0].y, -1.f, 1.f);
        fw[o][2] = med3(fwv[o][0].z, -1.f, 1.f); fw[o][3] = med3(fwv[o][0].w, -1.f, 1.f);
        fw[o][4] = med3(fwv[o][1].x, -1.f, 1.f); fw[o][5] = med3(fwv[o][1].y, -1.f, 1.f);
        fw[o][6] = med3(fwv[o][1].z, -1.f, 1.f); fw[o][7] = med3(fwv[o][1].w, -1.f, 1.f);
    }

    float t4[NL2];
    #pragma unroll
    for (int o = 0; o < NL2; ++o) {
        float d = 0.f;
        #pragma unroll
        for (int r = 0; r < NRC; ++r) d += fw[o][r] * rcv[r];
        t4[o] = x * d;
    }
    wave_sum4(t4);
    #pragma unroll
    for (int o = 0; o < NL2; ++o)
        l2v[o] = med3(0.1f * (rl63(t4[o]) + fb[o]), -0.2f, 1.0f);
    blur4(l2v); blur4(l2v);

    // ---- l1: rw read from LDS (swizzled), clamp at use ----
    asm volatile("s_waitcnt vmcnt(0)" ::: "memory");   // staging landed
    const float4* lrow = (const float4*)lbase;
    const int swz = safe & 7;      // junk lanes share lane-40 addr -> broadcast
    {
        float acc = rb;
        #pragma unroll
        for (int o = 0; o < NL2; ++o) {
            const float4 a = lrow[safe * 8 + ((2 * o)     ^ swz)];
            const float4 b = lrow[safe * 8 + ((2 * o + 1) ^ swz)];
            float d = 0.f;
            d += med3(a.x, -1.f, 1.f) * rcv[0];
            d += med3(a.y, -1.f, 1.f) * rcv[1];
            d += med3(a.z, -1.f, 1.f) * rcv[2];
            d += med3(a.w, -1.f, 1.f) * rcv[3];
            d += med3(b.x, -1.f, 1.f) * rcv[4];
            d += med3(b.y, -1.f, 1.f) * rcv[5];
            d += med3(b.z, -1.f, 1.f) * rcv[6];
            d += med3(b.w, -1.f, 1.f) * rcv[7];
            acc += l2v[o] * d;
        }
        l1 = med3(acc, -0.2f, 1.0f);
    }

    // ---------------- iteration 2 ----------------
    // reload w2 slice (688B table, L1-hot) instead of keeping it live
    __builtin_amdgcn_sched_barrier(0);   // pin reload here (short liveness)
    float corr[NRC];
    #pragma unroll
    for (int r = 0; r < NRC; ++r) {
        const float w2 = pgw[r * 86 + 45 + safe];
        corr[r] = act ? (l1 * w2) : 0.0f;
    }
    wave_sum8(corr);
    #pragma unroll
    for (int r = 0; r < NRC; ++r) {
        const float pre = A[r] - rl63(corr[r]);
        const float v = (pre >= 0.f) ? pre : 0.2f * pre;
        rcv[r] = med3(0.4f * v, -0.2f, 1.0f);
    }
    blur8(rcv); blur8(rcv); blur8(rcv);

    #pragma unroll
    for (int o = 0; o < NL2; ++o) {
        float d = 0.f;
        #pragma unroll
        for (int r = 0; r < NRC; ++r) d += fw[o][r] * rcv[r];
        t4[o] = x * d;
    }
    wave_sum4(t4);
    #pragma unroll
    for (int o = 0; o < NL2; ++o)
        l2v[o] = med3(0.1f * (rl63(t4[o]) + fb[o]), -0.2f, 1.0f);
    blur4(l2v); blur4(l2v);

    {
        float acc = rb;
        #pragma unroll
        for (int o = 0; o < NL2; ++o) {
            const float4 a = lrow[safe * 8 + ((2 * o)     ^ swz)];
            const float4 b = lrow[safe * 8 + ((2 * o + 1) ^ swz)];
            float d = 0.f;
            d += med3(a.x, -1.f, 1.f) * rcv[0];
            d += med3(a.y, -1.f, 1.f) * rcv[1];
            d += med3(a.z, -1.f, 1.f) * rcv[2];
            d += med3(a.w, -1.f, 1.f) * rcv[3];
            d += med3(b.x, -1.f, 1.f) * rcv[4];
            d += med3(b.y, -1.f, 1.f) * rcv[5];
            d += med3(b.z, -1.f, 1.f) * rcv[6];
            d += med3(b.w, -1.f, 1.f) * rcv[7];
            acc += l2v[o] * d;
        }
        l1 = med3(acc, -0.2f, 1.0f);
    }

    // ---------- stores: [l1i (B*41) | l2 (B*4) | rc (B*8)] ----------
    if (act) out[(size_t)row * NIN + lane] = l1;
    if (lane < NL2) {
        float v = l2v[0];
        #pragma unroll
        for (int o = 1; o < NL2; ++o) if (lane == o) v = l2v[o];
        out[(size_t)B_ROWS * NIN + (size_t)row * NL2 + lane] = v;
    }
    if (lane < NRC) {
        float v = rcv[0];
        #pragma unroll
        for (int r = 1; r < NRC; ++r) if (lane == r) v = rcv[r];
        out[(size_t)B_ROWS * (NIN + NL2) + (size_t)row * NRC + lane] = v;
    }
}

extern "C" void kernel_launch(void* const* d_in, const int* in_sizes, int n_in,
                              void* d_out, int out_size, void* d_ws, size_t ws_size,
                              hipStream_t stream) {
    const float* inp   = (const float*)d_in[0];
    const float* fpg_w = (const float*)d_in[1];
    const float* fpg_b = (const float*)d_in[2];
    const float* rpg_w = (const float*)d_in[3];
    const float* rpg_b = (const float*)d_in[4];
    const float* pgw   = (const float*)d_in[5];
    const float* pgb   = (const float*)d_in[6];
    float* out = (float*)d_out;

    dim3 grid(B_ROWS / 4);   // one wave per row
    dim3 block(256);
    hipLaunchKernelGGL(pgnet_kernel, grid, block, 0, stream,
                       inp, fpg_w, fpg_b, rpg_w, rpg_b, pgw, pgb, out);
}

// Round 3
// 360.171 us; speedup vs baseline: 1.0967x; 1.0967x over previous
//
#include <hip/hip_runtime.h>

#define B_ROWS 32768
#define NIN 41
#define NL2 4
#define NRC 8
#define ROW_F 1344   // LDS floats per staged rpg row (5376 B, 16B-aligned stride)

// clamp via single v_med3_f32
__device__ __forceinline__ float med3(float v, float lo, float hi) {
    return __builtin_amdgcn_fmed3f(v, lo, hi);
}

__device__ __forceinline__ float rl63(float v) {
    return __int_as_float(__builtin_amdgcn_readlane(__float_as_int(v), 63));
}

// async global->LDS, 16B per lane; dest is wave-uniform base + lane*16
__device__ __forceinline__ void stage16(const float* g, float* l) {
    __builtin_amdgcn_global_load_lds(
        (const __attribute__((address_space(1))) void*)g,
        (__attribute__((address_space(3))) void*)l,
        16, 0, 0);
}

// ---- fused-DPP batched wave reductions (one v_add_f32_dpp per step) -------
#define DPP8(C) \
    "v_add_f32_dpp %0, %0, %0 " C " row_mask:0xf bank_mask:0xf bound_ctrl:0\n\t" \
    "v_add_f32_dpp %1, %1, %1 " C " row_mask:0xf bank_mask:0xf bound_ctrl:0\n\t" \
    "v_add_f32_dpp %2, %2, %2 " C " row_mask:0xf bank_mask:0xf bound_ctrl:0\n\t" \
    "v_add_f32_dpp %3, %3, %3 " C " row_mask:0xf bank_mask:0xf bound_ctrl:0\n\t" \
    "v_add_f32_dpp %4, %4, %4 " C " row_mask:0xf bank_mask:0xf bound_ctrl:0\n\t" \
    "v_add_f32_dpp %5, %5, %5 " C " row_mask:0xf bank_mask:0xf bound_ctrl:0\n\t" \
    "v_add_f32_dpp %6, %6, %6 " C " row_mask:0xf bank_mask:0xf bound_ctrl:0\n\t" \
    "v_add_f32_dpp %7, %7, %7 " C " row_mask:0xf bank_mask:0xf bound_ctrl:0\n\t"

__device__ __forceinline__ void wave_sum8(float* v) {
    asm("s_nop 1\n\t"
        DPP8("row_shr:1")
        DPP8("row_shr:2")
        DPP8("row_shr:4")
        DPP8("row_shr:8")
        DPP8("row_bcast:15")
        DPP8("row_bcast:31")
        "s_nop 1"
        : "+v"(v[0]), "+v"(v[1]), "+v"(v[2]), "+v"(v[3]),
          "+v"(v[4]), "+v"(v[5]), "+v"(v[6]), "+v"(v[7]));
}

#define DPP4(C) \
    "v_add_f32_dpp %0, %0, %0 " C " row_mask:0xf bank_mask:0xf bound_ctrl:0\n\t" \
    "v_add_f32_dpp %1, %1, %1 " C " row_mask:0xf bank_mask:0xf bound_ctrl:0\n\t" \
    "v_add_f32_dpp %2, %2, %2 " C " row_mask:0xf bank_mask:0xf bound_ctrl:0\n\t" \
    "v_add_f32_dpp %3, %3, %3 " C " row_mask:0xf bank_mask:0xf bound_ctrl:0\n\t"

__device__ __forceinline__ void wave_sum4(float* v) {
    asm("s_nop 1\n\t"
        DPP4("row_shr:1")
        DPP4("row_shr:2")
        DPP4("row_shr:4")
        DPP4("row_shr:8")
        DPP4("row_bcast:15")
        DPP4("row_bcast:31")
        "s_nop 1"
        : "+v"(v[0]), "+v"(v[1]), "+v"(v[2]), "+v"(v[3]));
}

__device__ __forceinline__ void blur8(float* v) {
    float t[NRC];
    #pragma unroll
    for (int r = 0; r < NRC; ++r) {
        float s = 0.8f * v[r];
        if (r > 0)       s += 0.1f * v[r - 1];
        if (r < NRC - 1) s += 0.1f * v[r + 1];
        t[r] = s;
    }
    #pragma unroll
    for (int r = 0; r < NRC; ++r) v[r] = t[r];
}

__device__ __forceinline__ void blur4(float* v) {
    float t[NL2];
    #pragma unroll
    for (int o = 0; o < NL2; ++o) {
        float s = 0.8f * v[o];
        if (o > 0)       s += 0.1f * v[o - 1];
        if (o < NL2 - 1) s += 0.1f * v[o + 1];
        t[o] = s;
    }
    #pragma unroll
    for (int o = 0; o < NL2; ++o) v[o] = t[o];
}

// launch_bounds(256,5): VGPR cap ~102 (natural demand ~80 -> NO spill),
// 5 waves/SIMD = 20 waves/CU residency; LDS 21504B allows 7 blocks/CU.
// (256,6) in R2 forced VGPR=40 -> ~250MB scratch spill traffic, dur 156us.
__global__ void __launch_bounds__(256, 5) pgnet_kernel(
    const float* __restrict__ inp,
    const float* __restrict__ fpg_w,
    const float* __restrict__ fpg_b,
    const float* __restrict__ rpg_w,
    const float* __restrict__ rpg_b,
    const float* __restrict__ pgw,   // [8,86]
    const float* __restrict__ pgb,   // [8]
    float* __restrict__ out)
{
    __shared__ __align__(16) float lds_rw[4][ROW_F];

    const int lane = threadIdx.x & 63;
    const int w    = threadIdx.x >> 6;
    const int row  = blockIdx.x * 4 + w;
    const bool act = lane < NIN;
    const int safe = act ? lane : (NIN - 1);   // in-bounds address for all lanes

    // ---- group 1: pgctrl table (fused w1+w2), input, biases ----
    float ws[NRC];
    #pragma unroll
    for (int r = 0; r < NRC; ++r)
        ws[r] = pgw[r * 86 + safe] + pgw[r * 86 + 45 + safe];
    const float x_raw = inp[row * NIN + safe];
    const float4 fbv  = *(const float4*)(fpg_b + (size_t)row * NL2); // wave-uniform
    const float  rb_r = rpg_b[row * NIN + safe];
    __builtin_amdgcn_sched_barrier(0);

    // ---- group 2: fpg_w[b,o,i,r] into regs (only register payload kept) ----
    const float* fp = fpg_w + (size_t)row * 1312 + (size_t)safe * 8;
    float4 fwv[NL2][2];
    #pragma unroll
    for (int o = 0; o < NL2; ++o) {
        fwv[o][0] = *(const float4*)(fp + o * 328);
        fwv[o][1] = *(const float4*)(fp + o * 328 + 4);
    }
    __builtin_amdgcn_sched_barrier(0);

    // ---- group 3: stage rpg_w row into LDS, fully coalesced (1KB/instr) ----
    // LDS chunk d = k*64+lane holds global 16B-chunk (i*8 + j) where
    // i = d>>3, j = (d&7) ^ (i&7)  -> read-side XOR swizzle spreads the
    // per-lane 128B rows across all 8 bank-groups (conflict-free b128 reads).
    const float* rbase = rpg_w + (size_t)row * 1312;
    float* lbase = &lds_rw[w][0];
    #pragma unroll
    for (int k = 0; k < 5; ++k) {
        const int d = k * 64 + lane;
        const int i = d >> 3;
        const int j = (d & 7) ^ (i & 7);
        stage16(rbase + i * 32 + j * 4, lbase + k * 256);
    }
    if (lane < 8) {                    // tail: chunks 320..327 (i = 40)
        stage16(rbase + 40 * 32 + lane * 4, lbase + 5 * 256);
    }
    __builtin_amdgcn_sched_barrier(0);
    // ========================================================================

    const float x  = act ? x_raw : 0.0f;
    const float rb = act ? rb_r  : 0.0f;

    // A[r] = pgb[r] + sum_i x_i*(W[r,i]+W[r,45+i]) -- runs under load shadow
    float t8[NRC];
    #pragma unroll
    for (int r = 0; r < NRC; ++r) t8[r] = x * ws[r];
    wave_sum8(t8);
    float A[NRC];
    #pragma unroll
    for (int r = 0; r < NRC; ++r) A[r] = rl63(t8[r]) + pgb[r];

    const float fb[NL2] = {fbv.x, fbv.y, fbv.z, fbv.w};

    float l1, rcv[NRC], l2v[NL2];

    // ---------------- iteration 1 (l1i == 0 -> no corr) ----------------
    #pragma unroll
    for (int r = 0; r < NRC; ++r) {
        const float pre = A[r];
        const float v = (pre >= 0.f) ? pre : 0.2f * pre;
        rcv[r] = med3(0.4f * v, -0.2f, 1.0f);
    }
    blur8(rcv); blur8(rcv); blur8(rcv);

    // clamp fpg weights (first vmem wait: staging still in flight behind it)
    float fw[NL2][NRC];
    #pragma unroll
    for (int o = 0; o < NL2; ++o) {
        fw[o][0] = med3(fwv[o][0].x, -1.f, 1.f); fw[o][1] = med3(fwv[o][0].y, -1.f, 1.f);
        fw[o][2] = med3(fwv[o][0].z, -1.f, 1.f); fw[o][3] = med3(fwv[o][0].w, -1.f, 1.f);
        fw[o][4] = med3(fwv[o][1].x, -1.f, 1.f); fw[o][5] = med3(fwv[o][1].y, -1.f, 1.f);
        fw[o][6] = med3(fwv[o][1].z, -1.f, 1.f); fw[o][7] = med3(fwv[o][1].w, -1.f, 1.f);
    }

    float t4[NL2];
    #pragma unroll
    for (int o = 0; o < NL2; ++o) {
        float d = 0.f;
        #pragma unroll
        for (int r = 0; r < NRC; ++r) d += fw[o][r] * rcv[r];
        t4[o] = x * d;
    }
    wave_sum4(t4);
    #pragma unroll
    for (int o = 0; o < NL2; ++o)
        l2v[o] = med3(0.1f * (rl63(t4[o]) + fb[o]), -0.2f, 1.0f);
    blur4(l2v); blur4(l2v);

    // ---- l1: rw read from LDS (swizzled), clamp at use ----
    asm volatile("s_waitcnt vmcnt(0)" ::: "memory");   // staging landed
    const float4* lrow = (const float4*)lbase;
    const int swz = safe & 7;      // junk lanes share lane-40 addr -> broadcast
    {
        float acc = rb;
        #pragma unroll
        for (int o = 0; o < NL2; ++o) {
            const float4 a = lrow[safe * 8 + ((2 * o)     ^ swz)];
            const float4 b = lrow[safe * 8 + ((2 * o + 1) ^ swz)];
            float d = 0.f;
            d += med3(a.x, -1.f, 1.f) * rcv[0];
            d += med3(a.y, -1.f, 1.f) * rcv[1];
            d += med3(a.z, -1.f, 1.f) * rcv[2];
            d += med3(a.w, -1.f, 1.f) * rcv[3];
            d += med3(b.x, -1.f, 1.f) * rcv[4];
            d += med3(b.y, -1.f, 1.f) * rcv[5];
            d += med3(b.z, -1.f, 1.f) * rcv[6];
            d += med3(b.w, -1.f, 1.f) * rcv[7];
            acc += l2v[o] * d;
        }
        l1 = med3(acc, -0.2f, 1.0f);
    }

    // ---------------- iteration 2 ----------------
    // reload w2 slice (688B table, L1-hot) instead of keeping it live
    __builtin_amdgcn_sched_barrier(0);   // pin reload here (short liveness)
    float corr[NRC];
    #pragma unroll
    for (int r = 0; r < NRC; ++r) {
        const float w2 = pgw[r * 86 + 45 + safe];
        corr[r] = act ? (l1 * w2) : 0.0f;
    }
    wave_sum8(corr);
    #pragma unroll
    for (int r = 0; r < NRC; ++r) {
        const float pre = A[r] - rl63(corr[r]);
        const float v = (pre >= 0.f) ? pre : 0.2f * pre;
        rcv[r] = med3(0.4f * v, -0.2f, 1.0f);
    }
    blur8(rcv); blur8(rcv); blur8(rcv);

    #pragma unroll
    for (int o = 0; o < NL2; ++o) {
        float d = 0.f;
        #pragma unroll
        for (int r = 0; r < NRC; ++r) d += fw[o][r] * rcv[r];
        t4[o] = x * d;
    }
    wave_sum4(t4);
    #pragma unroll
    for (int o = 0; o < NL2; ++o)
        l2v[o] = med3(0.1f * (rl63(t4[o]) + fb[o]), -0.2f, 1.0f);
    blur4(l2v); blur4(l2v);

    {
        float acc = rb;
        #pragma unroll
        for (int o = 0; o < NL2; ++o) {
            const float4 a = lrow[safe * 8 + ((2 * o)     ^ swz)];
            const float4 b = lrow[safe * 8 + ((2 * o + 1) ^ swz)];
            float d = 0.f;
            d += med3(a.x, -1.f, 1.f) * rcv[0];
            d += med3(a.y, -1.f, 1.f) * rcv[1];
            d += med3(a.z, -1.f, 1.f) * rcv[2];
            d += med3(a.w, -1.f, 1.f) * rcv[3];
            d += med3(b.x, -1.f, 1.f) * rcv[4];
            d += med3(b.y, -1.f, 1.f) * rcv[5];
            d += med3(b.z, -1.f, 1.f) * rcv[6];
            d += med3(b.w, -1.f, 1.f) * rcv[7];
            acc += l2v[o] * d;
        }
        l1 = med3(acc, -0.2f, 1.0f);
    }

    // ---------- stores: [l1i (B*41) | l2 (B*4) | rc (B*8)] ----------
    if (act) out[(size_t)row * NIN + lane] = l1;
    if (lane < NL2) {
        float v = l2v[0];
        #pragma unroll
        for (int o = 1; o < NL2; ++o) if (lane == o) v = l2v[o];
        out[(size_t)B_ROWS * NIN + (size_t)row * NL2 + lane] = v;
    }
    if (lane < NRC) {
        float v = rcv[0];
        #pragma unroll
        for (int r = 1; r < NRC; ++r) if (lane == r) v = rcv[r];
        out[(size_t)B_ROWS * (NIN + NL2) + (size_t)row * NRC + lane] = v;
    }
}

extern "C" void kernel_launch(void* const* d_in, const int* in_sizes, int n_in,
                              void* d_out, int out_size, void* d_ws, size_t ws_size,
                              hipStream_t stream) {
    const float* inp   = (const float*)d_in[0];
    const float* fpg_w = (const float*)d_in[1];
    const float* fpg_b = (const float*)d_in[2];
    const float* rpg_w = (const float*)d_in[3];
    const float* rpg_b = (const float*)d_in[4];
    const float* pgw   = (const float*)d_in[5];
    const float* pgb   = (const float*)d_in[6];
    float* out = (float*)d_out;

    dim3 grid(B_ROWS / 4);   // one wave per row
    dim3 block(256);
    hipLaunchKernelGGL(pgnet_kernel, grid, block, 0, stream,
                       inp, fpg_w, fpg_b, rpg_w, rpg_b, pgw, pgb, out);
}